// Round 1
// 154.223 us; speedup vs baseline: 1.0383x; 1.0383x over previous
//
#include <hip/hip_runtime.h>
#include <math.h>

#define B_ 64
#define S_ 129
#define F_ 768
#define N3 192            // 3*B
#define GSZ 36864         // 192*192
#define GRID_MAIN 252     // 12 f-columns x 21 s-groups

// ws float offsets
#define WS_S1   0
#define WS_S2   49152
#define WS_PART 98304

// out float offsets
#define OUT_LOSS 6340608
#define OUT_NM   6340609
#define OUT_NV   6343681

typedef unsigned int uint;
using short8v = __attribute__((ext_vector_type(8))) short;
using float4v = __attribute__((ext_vector_type(4))) float;

// ---------------- K1: per-(b,f) sums over S, fused S-split + LDS reduce ------------
__global__ void k_stats(const float* __restrict__ x,
                        float* __restrict__ s1, float* __restrict__ s2,
                        float* __restrict__ out_loss) {
    __shared__ float4 r1[256], r2[256];
    if (blockIdx.x == 0 && threadIdx.x == 0) out_loss[0] = 0.0f;
    int b = blockIdx.x / 3, fg = blockIdx.x % 3;
    int c = threadIdx.x & 63, sp = threadIdx.x >> 6;
    int f = fg * 256 + c * 4;
    const float* p = x + (size_t)b * S_ * F_ + f;
    int s0 = sp * 32;
    int se = s0 + 32 + (sp == 3 ? 1 : 0);
    float4 a1 = {0.f,0.f,0.f,0.f}, a2 = {0.f,0.f,0.f,0.f};
#pragma unroll 4
    for (int s = s0; s < se; ++s) {
        float4 v = *(const float4*)(p + s * F_);
        a1.x += v.x; a1.y += v.y; a1.z += v.z; a1.w += v.w;
        a2.x += v.x*v.x; a2.y += v.y*v.y; a2.z += v.z*v.z; a2.w += v.w*v.w;
    }
    r1[threadIdx.x] = a1; r2[threadIdx.x] = a2;
    __syncthreads();
    if (sp == 0) {
        float4 t1 = r1[c], t2 = r2[c];
#pragma unroll
        for (int k = 1; k < 4; ++k) {
            float4 u1 = r1[k * 64 + c], u2 = r2[k * 64 + c];
            t1.x += u1.x; t1.y += u1.y; t1.z += u1.z; t1.w += u1.w;
            t2.x += u2.x; t2.y += u2.y; t2.z += u2.z; t2.w += u2.w;
        }
        *(float4*)(s1 + b * F_ + f) = t1;
        *(float4*)(s2 + b * F_ + f) = t2;
    }
}

// ---------------- bf16 helpers ----------------
__device__ __forceinline__ uint pack2(float a, float b) {
    uint ua = __float_as_uint(a);
    uint ub = __float_as_uint(b);
    uint ha = (ua + 0x7FFFu + ((ua >> 16) & 1u)) >> 16;
    uint hb = (ub + 0x7FFFu + ((ub >> 16) & 1u)) & 0xFFFF0000u;
    return hb | ha;
}

__device__ __forceinline__ void bf16_store8(char* lds, int row, int g,
                                            float4 v0, float4 v1) {
    uint4 H;
    H.x = pack2(v0.x, v0.y);
    H.y = pack2(v0.z, v0.w);
    H.z = pack2(v1.x, v1.y);
    H.w = pack2(v1.z, v1.w);
    *(uint4*)(lds + row * 128 + ((g ^ (row & 7)) << 4)) = H;
}

__device__ __forceinline__ float4 fma4(float4 a, float4 x, float4 b) {
    float4 r;
    r.x = fmaf(a.x, x.x, b.x); r.y = fmaf(a.y, x.y, b.y);
    r.z = fmaf(a.z, x.z, b.z); r.w = fmaf(a.w, x.w, b.w);
    return r;
}

// ---------------- K2: fused dom-stats + coef + x_mix/hg gen + MFMA Gram -------------
// 252 blocks x 512 threads. Block owns a fixed 64-float f-column (fc = bid%12) and
// s = sb, sb+21, ... : coefficients are s-invariant -> computed ONCE into registers
// (folds the old k_dom + k_coef kernels; dom stats recomputed redundantly per block
// from s1/s2, ~64x64x2 L2 loads). Per-chunk global loads drop 192B -> 64B/thread.
// NOTE (r9 post-mortem): depth-2 prefetch spilled acc to scratch — keep flat depth-1.
template <bool EXCL>
__global__ __launch_bounds__(512, 2)
void k_main(const float* __restrict__ x, const float* __restrict__ hgn,
            const float* __restrict__ s1, const float* __restrict__ s2,
            const float* __restrict__ mean_buf, const float* __restrict__ var_buf,
            const float* __restrict__ lmda, const int* __restrict__ domain,
            const int* __restrict__ d_rand,
            float* __restrict__ xmix, float* __restrict__ out_nm,
            float* __restrict__ out_nv,
            float* part, int npart) {
    __shared__ __align__(16) char LDS[25088];   // main: 192x128B bf16; epi: 32x196 f32
    __shared__ float NMV[4][64];
    __shared__ float SVV[4][64];

    int tid = threadIdx.x;
    int bid = blockIdx.x;
    int fc = bid % 12, sb = bid / 12;
    int f0 = fc * 64;
    int b = tid >> 3, g = tid & 7;
    int w = tid >> 6;
    int wr = (w >> 2) * 96, wc = (w & 3) * 48;
    int lane = tid & 63, m = lane & 15, qd = lane >> 4;

    // issue first-chunk streaming loads early (hide prologue latency under them)
    int s = sb;
    size_t goff = ((size_t)b * S_ + s) * F_ + f0 + (g << 3);
    float4 X0 = ((const float4*)(x + goff))[0];
    float4 X1 = ((const float4*)(x + goff))[1];
    float4 N0 = ((const float4*)(hgn + goff))[0];
    float4 N1 = ((const float4*)(hgn + goff))[1];

    // ---- folded k_dom: per-(d,f) EMA stats for this block's f-column ----
    if (tid < 256) {
        int d = tid & 3, fl = tid >> 2;
        int f = f0 + fl;
        float a1 = 0.f, a2 = 0.f, cnt = 0.f;
#pragma unroll 8
        for (int bb = 0; bb < B_; ++bb) {
            bool mk = (domain[bb] == d);
            a1  += mk ? s1[bb * F_ + f] : 0.f;
            a2  += mk ? s2[bb * F_ + f] : 0.f;
            cnt += mk ? 1.f : 0.f;
        }
        float nm, nv;
        if (cnt > 0.f) {
            float n = cnt * (float)S_;
            float mu = a1 / n;
            float var = (a2 - n * mu * mu) / fmaxf(n - 1.f, 1.f);
            nm = 0.9f * mean_buf[d * F_ + f] + 0.1f * mu;
            nv = 0.9f * var_buf[d * F_ + f] + 0.1f * var;
        } else {
            nm = mean_buf[d * F_ + f];
            nv = var_buf[d * F_ + f];
        }
        NMV[d][fl] = nm;
        SVV[d][fl] = sqrtf(nv + 1e-6f);
        if (sb == 0) { out_nm[d * F_ + f] = nm; out_nv[d * F_ + f] = nv; }
    }
    __syncthreads();

    // ---- folded k_coef: per-thread mix/hg coefficients, held in regs all kernel ----
    int cb = b * F_ + f0 + (g << 3);
    float4 S1a = ((const float4*)(s1 + cb))[0], S1b = ((const float4*)(s1 + cb))[1];
    float4 S2a = ((const float4*)(s2 + cb))[0], S2b = ((const float4*)(s2 + cb))[1];
    int dm = domain[b];
    int dsd = (dm + d_rand[b]) & 3;              // D == 4
    float lam = lmda[b];
    float4 C1a, C1b, C0a, C0b, HMa, HMb, HSa, HSb;
#define COEF(SC1, SC2, FL, RC1, RC0, RHM, RHS) {            \
        float mu = (SC1) * (1.0f / (float)S_);              \
        float v  = ((SC2) - (float)S_ * mu * mu) * (1.0f / (float)(S_ - 1)); \
        float r  = rsqrtf(v + 1e-6f);                       \
        float sv = SVV[dsd][FL];                            \
        float rs = r * sv;                                  \
        RC1 = lam + (1.0f - lam) * rs;                      \
        RC0 = (1.0f - lam) * (NMV[dsd][FL] - mu * rs);      \
        RHM = NMV[dm][FL];                                  \
        RHS = SVV[dm][FL]; }
    {
        int fb = g << 3;
        COEF(S1a.x, S2a.x, fb + 0, C1a.x, C0a.x, HMa.x, HSa.x);
        COEF(S1a.y, S2a.y, fb + 1, C1a.y, C0a.y, HMa.y, HSa.y);
        COEF(S1a.z, S2a.z, fb + 2, C1a.z, C0a.z, HMa.z, HSa.z);
        COEF(S1a.w, S2a.w, fb + 3, C1a.w, C0a.w, HMa.w, HSa.w);
        COEF(S1b.x, S2b.x, fb + 4, C1b.x, C0b.x, HMb.x, HSb.x);
        COEF(S1b.y, S2b.y, fb + 5, C1b.y, C0b.y, HMb.y, HSb.y);
        COEF(S1b.z, S2b.z, fb + 6, C1b.z, C0b.z, HMb.z, HSb.z);
        COEF(S1b.w, S2b.w, fb + 7, C1b.w, C0b.w, HMb.w, HSb.w);
    }
#undef COEF

    float4v acc[6][3];
#pragma unroll
    for (int i = 0; i < 6; ++i)
#pragma unroll
        for (int j = 0; j < 3; ++j)
            acc[i][j] = (float4v){0.f, 0.f, 0.f, 0.f};

    // ---- main loop: ~6 chunks at fixed f0, stride 21 in s ----
    for (; s < S_; s += 21) {
        float4 M0 = fma4(C1a, X0, C0a);
        float4 M1 = fma4(C1b, X1, C0b);
        ((float4*)(xmix + goff))[0] = M0;
        ((float4*)(xmix + goff))[1] = M1;
        float4 H0 = fma4(HSa, N0, HMa);
        float4 H1 = fma4(HSb, N1, HMb);

        bf16_store8(LDS, b, g, X0, X1);
        bf16_store8(LDS, 64 + b, g, M0, M1);
        bf16_store8(LDS, 128 + b, g, H0, H1);
        __syncthreads();

        // prefetch next chunk (x, hgn only — coefs live in regs)
        int sn = s + 21;
        if (sn < S_) {
            goff = ((size_t)b * S_ + sn) * F_ + f0 + (g << 3);
            X0 = ((const float4*)(x + goff))[0];
            X1 = ((const float4*)(x + goff))[1];
            N0 = ((const float4*)(hgn + goff))[0];
            N1 = ((const float4*)(hgn + goff))[1];
        }

#pragma unroll
        for (int t = 0; t < 2; ++t) {
            short8v A[6];
#pragma unroll
            for (int i = 0; i < 6; ++i) {
                int row = wr + i * 16 + m;
                int go = (((t << 2) + qd) ^ (row & 7)) << 4;
                A[i] = *(const short8v*)(LDS + row * 128 + go);
            }
#pragma unroll
            for (int j = 0; j < 3; ++j) {
                int row = wc + j * 16 + m;
                int go = (((t << 2) + qd) ^ (row & 7)) << 4;
                short8v Bv = *(const short8v*)(LDS + row * 128 + go);
#pragma unroll
                for (int i = 0; i < 6; ++i)
                    acc[i][j] = __builtin_amdgcn_mfma_f32_16x16x32_bf16(A[i], Bv, acc[i][j], 0, 0, 0);
            }
        }
        __syncthreads();
    }

    // ---- epilogue: LDS-transpose each 16-row band, store coalesced float4 ----
    // old path: 288 scalar stores/thread in 64B scattered segments; now 18 float4.
    float* T = (float*)LDS;                      // [32][196] f32, pad breaks bank alias
    const int PADW = 196;
    float* dst = part + (size_t)(bid % npart) * GSZ;
    int lrb = (wr ? 16 : 0) + (qd << 2);
    int lr2 = tid >> 4;
#pragma unroll
    for (int i = 0; i < 6; ++i) {
        __syncthreads();                          // protect previous iter's reads
#pragma unroll
        for (int j = 0; j < 3; ++j) {
            int colb = wc + j * 16 + m;
#pragma unroll
            for (int r = 0; r < 4; ++r)
                T[(lrb + r) * PADW + colb] = acc[i][j][r];
        }
        __syncthreads();
        int grow = i * 16 + (lr2 & 15) + (lr2 >> 4) * 96;
#pragma unroll
        for (int k = 0; k < 3; ++k) {
            int c4 = k * 16 + (tid & 15);
            float4 vv = *(const float4*)&T[lr2 * PADW + (c4 << 2)];
            int o = grow * N3 + (c4 << 2);
            if (EXCL) {
                *(float4*)(dst + o) = vv;
            } else {
                atomicAdd(dst + o + 0, vv.x);
                atomicAdd(dst + o + 1, vv.y);
                atomicAdd(dst + o + 2, vv.z);
                atomicAdd(dst + o + 3, vv.w);
            }
        }
    }
}

// ---------------- K3: reduce partial Grams (direct write, no atomics) -------------
__global__ void k_red(const float* __restrict__ part, float* __restrict__ gram, int npart) {
    int j = blockIdx.x * 256 + threadIdx.x;      // 0..36863
    float s = 0.0f;
#pragma unroll 8
    for (int p = 0; p < npart; ++p) s += part[(size_t)p * GSZ + j];
    gram[j] = s;
}

// ---------------- K4: triplet hard loss (one block per row) ----------------
__global__ void k_loss(const float* __restrict__ gram, const int* __restrict__ labels,
                       float* __restrict__ out_loss) {
    __shared__ float sq[N3];
    __shared__ int ln[N3];
    int i = blockIdx.x, lane = threadIdx.x;      // 64 lanes
    for (int k = lane; k < N3; k += 64) {
        sq[k] = gram[k * (N3 + 1)];
        ln[k] = (k < 128) ? labels[k & 63] : -1;
    }
    __syncthreads();
    int li = ln[i];
    float si = sq[i];
    float ap = -1e30f, an = 1e30f;
    for (int j = lane; j < N3; j += 64) {
        float d2 = si + sq[j] - 2.0f * gram[i * N3 + j];
        float dist = sqrtf(fmaxf(d2, 1e-12f));
        bool pos = (li == ln[j]);
        ap = pos ? fmaxf(ap, dist) : ap;
        an = pos ? an : fminf(an, dist);
    }
#pragma unroll
    for (int off = 32; off; off >>= 1) {
        ap = fmaxf(ap, __shfl_xor(ap, off));
        an = fminf(an, __shfl_xor(an, off));
    }
    if (lane == 0) {
        float xv = ap - an;
        float sp = fmaxf(xv, 0.0f) + log1pf(expf(-fabsf(xv)));
        atomicAdd(out_loss, sp * (1.0f / (float)N3));
    }
}

extern "C" void kernel_launch(void* const* d_in, const int* in_sizes, int n_in,
                              void* d_out, int out_size, void* d_ws, size_t ws_size,
                              hipStream_t stream) {
    const float* x        = (const float*)d_in[0];
    const float* lmda     = (const float*)d_in[1];
    const float* mean_buf = (const float*)d_in[2];
    const float* var_buf  = (const float*)d_in[3];
    const float* hgn      = (const float*)d_in[4];
    const int*   labels   = (const int*)d_in[5];
    const int*   domain   = (const int*)d_in[6];
    const int*   d_rand   = (const int*)d_in[7];
    float* out = (float*)d_out;
    float* ws  = (float*)d_ws;

    long avail = (long)(ws_size / 4) - WS_PART;
    int npart = (int)(avail / GSZ) - 1;          // reserve one slice for gram
    if (npart < 1) npart = 1;
    if (npart > GRID_MAIN) npart = GRID_MAIN;
    bool excl = (npart == GRID_MAIN);
    float* part = ws + WS_PART;
    float* gram = ws + WS_PART + (size_t)npart * GSZ;

    k_stats<<<dim3(192), dim3(256), 0, stream>>>(x, ws + WS_S1, ws + WS_S2,
                                                 out + OUT_LOSS);
    if (!excl) {
        hipMemsetAsync(part, 0, (size_t)npart * GSZ * 4, stream);
    }
    if (excl) {
        k_main<true><<<dim3(GRID_MAIN), dim3(512), 0, stream>>>(
            x, hgn, ws + WS_S1, ws + WS_S2, mean_buf, var_buf,
            lmda, domain, d_rand,
            out, out + OUT_NM, out + OUT_NV, part, npart);
    } else {
        k_main<false><<<dim3(GRID_MAIN), dim3(512), 0, stream>>>(
            x, hgn, ws + WS_S1, ws + WS_S2, mean_buf, var_buf,
            lmda, domain, d_rand,
            out, out + OUT_NM, out + OUT_NV, part, npart);
    }
    k_red<<<dim3(144), dim3(256), 0, stream>>>(part, gram, npart);
    k_loss<<<dim3(N3), dim3(64), 0, stream>>>(gram, labels, out + OUT_LOSS);
}